// Round 2
// baseline (113.498 us; speedup 1.0000x reference)
//
#include <hip/hip_runtime.h>
#include <math.h>

// ---------------------------------------------------------------------------
// Difflogic network, collapsed form:
//   per neuron: out = c0 + c1*p + c2*q + c3*p*q,  p = A·x, q = B·x
//   A,B = softmax(sel), (c0..c3) = softmax(gate_logits) · gate-coef table
//
// ws layout (floats):
//   A1:   0 (72)   B1:  72 (72)   C1: 144 (32)
//   A2: 176 (32)   B2: 208 (32)   C2: 240 (16)
//   A3: 256 ( 8)   B3: 264 ( 8)   C3: 272 ( 8)
//   A4: 280 ( 2)   B4: 282 ( 2)   C4: 284 ( 4)   total 288 floats = 1152 B
// ---------------------------------------------------------------------------

#define THREADS 256
#define SPT 4                    // samples per thread
#define B_PER_BLOCK (THREADS * SPT)   // 1024 samples / block

__global__ void coeff_kernel(const float* sa1, const float* sb1, const float* g1,
                             const float* sa2, const float* sb2, const float* g2,
                             const float* sa3, const float* sb3, const float* g3,
                             const float* sa4, const float* sb4, const float* g4,
                             float* cf) {
    int t = threadIdx.x;
    // difflogic gate ordering -> coefficients of (1, p, q, pq)
    const float k0[16]  = {0,0,0,0, 0,0,0,0, 1, 1, 1, 1, 1, 1, 1, 1};
    const float kp[16]  = {0,0,1,1, 0,0,1,1,-1,-1, 0, 0,-1,-1, 0, 0};
    const float kq[16]  = {0,0,0,0, 1,1,1,1,-1,-1,-1,-1, 0, 0, 0, 0};
    const float kpq[16] = {0,1,-1,0,-1,0,-2,-1, 1, 2, 0, 1, 0, 1,-1, 0};

    const float *sa, *sb, *g;
    float *A, *Bc, *C;
    int d;
    if (t < 8)       { int j = t;      d = 9; sa = sa1 + j*9; sb = sb1 + j*9; g = g1 + j*16; A = cf       + j*9; Bc = cf +  72 + j*9; C = cf + 144 + j*4; }
    else if (t < 12) { int j = t - 8;  d = 8; sa = sa2 + j*8; sb = sb2 + j*8; g = g2 + j*16; A = cf + 176 + j*8; Bc = cf + 208 + j*8; C = cf + 240 + j*4; }
    else if (t < 14) { int j = t - 12; d = 4; sa = sa3 + j*4; sb = sb3 + j*4; g = g3 + j*16; A = cf + 256 + j*4; Bc = cf + 264 + j*4; C = cf + 272 + j*4; }
    else if (t == 14){                 d = 2; sa = sa4;       sb = sb4;       g = g4;        A = cf + 280;       Bc = cf + 282;       C = cf + 284; }
    else return;

    {   // softmax(sel_a) -> A
        float m = -1e30f;
        for (int i = 0; i < d; ++i) m = fmaxf(m, sa[i]);
        float e[9], s = 0.f;
        for (int i = 0; i < d; ++i) { e[i] = expf(sa[i] - m); s += e[i]; }
        for (int i = 0; i < d; ++i) A[i] = e[i] / s;
    }
    {   // softmax(sel_b) -> B
        float m = -1e30f;
        for (int i = 0; i < d; ++i) m = fmaxf(m, sb[i]);
        float e[9], s = 0.f;
        for (int i = 0; i < d; ++i) { e[i] = expf(sb[i] - m); s += e[i]; }
        for (int i = 0; i < d; ++i) Bc[i] = e[i] / s;
    }
    {   // softmax(gate_logits) folded against gate-coef table -> C[0..3]
        float m = -1e30f;
        for (int i = 0; i < 16; ++i) m = fmaxf(m, g[i]);
        float w[16], s = 0.f;
        for (int i = 0; i < 16; ++i) { w[i] = expf(g[i] - m); s += w[i]; }
        float c0 = 0, c1 = 0, c2 = 0, c3 = 0;
        for (int i = 0; i < 16; ++i) {
            float wi = w[i] / s;
            c0 += wi * k0[i]; c1 += wi * kp[i]; c2 += wi * kq[i]; c3 += wi * kpq[i];
        }
        C[0] = c0; C[1] = c1; C[2] = c2; C[3] = c3;
    }
}

__global__ __launch_bounds__(THREADS) void net_kernel(
        const float* __restrict__ x, const float* __restrict__ cf,
        float* __restrict__ out, int nB) {
    // Stage this block's 1024 rows (9216 floats = 36 KB) via coalesced float4.
    __shared__ float sx[B_PER_BLOCK * 9];
    const int t = threadIdx.x;
    const long blockBase = (long)blockIdx.x * B_PER_BLOCK;
    const long elemBase  = blockBase * 9;          // float index; /4 is exact (9216/blk)
    const long total     = (long)nB * 9;

    const float4* __restrict__ x4 = (const float4*)x;
    float4* sx4 = (float4*)sx;
    #pragma unroll
    for (int k = 0; k < 9; ++k) {                  // 2304 float4 / 256 threads
        long fi = elemBase / 4 + t + k * 256;      // float4 index
        long e  = fi * 4;
        if (e + 3 < total) {
            sx4[t + k * 256] = x4[fi];
        } else {
            float4 v = {0.f, 0.f, 0.f, 0.f};
            if (e     < total) v.x = x[e];
            if (e + 1 < total) v.y = x[e + 1];
            if (e + 2 < total) v.z = x[e + 2];
            sx4[t + k * 256] = v;
        }
    }
    __syncthreads();

    #pragma unroll
    for (int s = 0; s < SPT; ++s) {
        const int  r = s * THREADS + t;            // local row; lane-stride 9 words in LDS
        const long b = blockBase + r;
        if (b >= nB) continue;

        float v[9];
        #pragma unroll
        for (int i = 0; i < 9; ++i) v[i] = sx[r * 9 + i];

        // Layer 1: 9 -> 8.  All cf[] indices are compile-time constants and
        // wave-uniform -> compiler emits s_load (SMEM pipe), operands in SGPRs.
        float h1[8];
        #pragma unroll
        for (int j = 0; j < 8; ++j) {
            float p = 0.f, q = 0.f;
            #pragma unroll
            for (int i = 0; i < 9; ++i) {
                p = fmaf(v[i], cf[      j * 9 + i], p);
                q = fmaf(v[i], cf[ 72 + j * 9 + i], q);
            }
            h1[j] = fmaf(cf[144 + j*4 + 3], p * q,
                    fmaf(cf[144 + j*4 + 2], q,
                    fmaf(cf[144 + j*4 + 1], p, cf[144 + j*4 + 0])));
        }
        // Layer 2: 8 -> 4
        float h2[4];
        #pragma unroll
        for (int j = 0; j < 4; ++j) {
            float p = 0.f, q = 0.f;
            #pragma unroll
            for (int i = 0; i < 8; ++i) {
                p = fmaf(h1[i], cf[176 + j * 8 + i], p);
                q = fmaf(h1[i], cf[208 + j * 8 + i], q);
            }
            h2[j] = fmaf(cf[240 + j*4 + 3], p * q,
                    fmaf(cf[240 + j*4 + 2], q,
                    fmaf(cf[240 + j*4 + 1], p, cf[240 + j*4 + 0])));
        }
        // Layer 3: 4 -> 2
        float h3[2];
        #pragma unroll
        for (int j = 0; j < 2; ++j) {
            float p = 0.f, q = 0.f;
            #pragma unroll
            for (int i = 0; i < 4; ++i) {
                p = fmaf(h2[i], cf[256 + j * 4 + i], p);
                q = fmaf(h2[i], cf[264 + j * 4 + i], q);
            }
            h3[j] = fmaf(cf[272 + j*4 + 3], p * q,
                    fmaf(cf[272 + j*4 + 2], q,
                    fmaf(cf[272 + j*4 + 1], p, cf[272 + j*4 + 0])));
        }
        // Layer 4: 2 -> 1
        {
            float p = fmaf(h3[0], cf[280], h3[1] * cf[281]);
            float q = fmaf(h3[0], cf[282], h3[1] * cf[283]);
            float o = fmaf(cf[287], p * q,
                      fmaf(cf[286], q,
                      fmaf(cf[285], p, cf[284])));
            out[b] = o;
        }
    }
}

extern "C" void kernel_launch(void* const* d_in, const int* in_sizes, int n_in,
                              void* d_out, int out_size, void* d_ws, size_t ws_size,
                              hipStream_t stream) {
    const float* x   = (const float*)d_in[0];
    const float* sa1 = (const float*)d_in[1];
    const float* sb1 = (const float*)d_in[2];
    const float* g1  = (const float*)d_in[3];
    const float* sa2 = (const float*)d_in[4];
    const float* sb2 = (const float*)d_in[5];
    const float* g2  = (const float*)d_in[6];
    const float* sa3 = (const float*)d_in[7];
    const float* sb3 = (const float*)d_in[8];
    const float* g3  = (const float*)d_in[9];
    const float* sa4 = (const float*)d_in[10];
    const float* sb4 = (const float*)d_in[11];
    const float* g4  = (const float*)d_in[12];
    float* cf = (float*)d_ws;                 // 288 floats of scratch
    const int nB = in_sizes[0] / 9;

    coeff_kernel<<<1, 64, 0, stream>>>(sa1, sb1, g1, sa2, sb2, g2,
                                       sa3, sb3, g3, sa4, sb4, g4, cf);
    const int grid = (nB + B_PER_BLOCK - 1) / B_PER_BLOCK;
    net_kernel<<<grid, THREADS, 0, stream>>>(x, cf, (float*)d_out, nB);
}